// Round 1
// baseline (999.013 us; speedup 1.0000x reference)
//
#include <hip/hip_runtime.h>
#include <math.h>

#define N_NODES 100000
#define N_EDGES 1280000
#define DIM 64
#define N_GRAPHS 1000
#define BN_EPS 1e-5f

// ---------------- degree / norm ----------------
__global__ void k_deg(const int* __restrict__ ei, int* __restrict__ degc) {
    int e = blockIdx.x * blockDim.x + threadIdx.x;
    if (e < N_EDGES) atomicAdd(&degc[ei[N_EDGES + e]], 1);
}

__global__ void k_dinv(const int* __restrict__ degc, float* __restrict__ dinv) {
    int i = blockIdx.x * blockDim.x + threadIdx.x;
    if (i < N_NODES) dinv[i] = 1.0f / sqrtf((float)(degc[i] + 1)); // +1 self-loop, deg>=1 always
}

// ---------------- BN statistics ----------------
// thread j = feature, 4 row-groups per block, grid-stride over rows
__global__ void k_stats_x(const float* __restrict__ X,
                          float* __restrict__ gsum, float* __restrict__ gsumsq) {
    int j = threadIdx.x & 63, rg = threadIdx.x >> 6;
    float s = 0.f, s2 = 0.f;
    for (int i = blockIdx.x * 4 + rg; i < N_NODES; i += gridDim.x * 4) {
        float v = X[i * DIM + j];
        s += v; s2 += v * v;
    }
    __shared__ float ls[256], ls2[256];
    ls[threadIdx.x] = s; ls2[threadIdx.x] = s2;
    __syncthreads();
    if (threadIdx.x < 64) {
        s  = ls[j]  + ls[64 + j]  + ls[128 + j]  + ls[192 + j];
        s2 = ls2[j] + ls2[64 + j] + ls2[128 + j] + ls2[192 + j];
        atomicAdd(&gsum[j], s);
        atomicAdd(&gsumsq[j], s2);
    }
}

// H = relu(C) stored; stats over relu(C)
__global__ void k_stats_relu(const float* __restrict__ C, float* __restrict__ H,
                             float* __restrict__ gsum, float* __restrict__ gsumsq) {
    int j = threadIdx.x & 63, rg = threadIdx.x >> 6;
    float s = 0.f, s2 = 0.f;
    for (int i = blockIdx.x * 4 + rg; i < N_NODES; i += gridDim.x * 4) {
        float v = fmaxf(C[i * DIM + j], 0.f);
        H[i * DIM + j] = v;
        s += v; s2 += v * v;
    }
    __shared__ float ls[256], ls2[256];
    ls[threadIdx.x] = s; ls2[threadIdx.x] = s2;
    __syncthreads();
    if (threadIdx.x < 64) {
        s  = ls[j]  + ls[64 + j]  + ls[128 + j]  + ls[192 + j];
        s2 = ls2[j] + ls2[64 + j] + ls2[128 + j] + ls2[192 + j];
        atomicAdd(&gsum[j], s);
        atomicAdd(&gsumsq[j], s2);
    }
}

// scale = g*rsqrt(var+eps); shift = b - mean*scale
__global__ void k_bnfinal(const float* __restrict__ gsum, const float* __restrict__ gsumsq,
                          const float* __restrict__ g, const float* __restrict__ b,
                          float* __restrict__ scale, float* __restrict__ shift) {
    int j = threadIdx.x;
    float mean = gsum[j] * (1.0f / N_NODES);
    float var  = gsumsq[j] * (1.0f / N_NODES) - mean * mean;
    float inv  = 1.0f / sqrtf(var + BN_EPS);
    float sc   = g[j] * inv;
    scale[j] = sc;
    shift[j] = b[j] - mean * sc;
}

// cshift[j] = sum_k shift[k] * W[k][j]  (BN shift folded through the GEMM)
__global__ void k_foldbias(const float* __restrict__ W, const float* __restrict__ shift,
                           float* __restrict__ cshift) {
    int j = threadIdx.x;
    float s = 0.f;
    for (int k = 0; k < DIM; k++) s += shift[k] * W[k * DIM + j];
    cshift[j] = s;
}

// ---------------- GEMM: T = (X*scale) @ W + cshift ----------------
// block = 256 threads, 64 rows per block. W (scale-folded) + 64x65-padded A tile in LDS.
__global__ __launch_bounds__(256) void k_gemm(const float* __restrict__ X,
                                              const float* __restrict__ W,
                                              const float* __restrict__ scale,
                                              const float* __restrict__ cshift,
                                              float* __restrict__ T) {
    __shared__ float Wl[64 * 64];
    __shared__ float Al[64 * 65];
    for (int t = threadIdx.x; t < 4096; t += 256) {
        int k = t >> 6;
        Wl[t] = W[t] * scale[k];
    }
    int row0 = blockIdx.x * 64;
    for (int t = threadIdx.x; t < 4096; t += 256) {
        int r = t >> 6, k = t & 63;
        int i = row0 + r;
        Al[r * 65 + k] = (i < N_NODES) ? X[i * DIM + k] : 0.f;
    }
    __syncthreads();

    int r = threadIdx.x & 63;
    int q = threadIdx.x >> 6;          // quarter: cols q*16 .. q*16+15
    float acc[16];
    #pragma unroll
    for (int jj = 0; jj < 16; jj++) acc[jj] = cshift[q * 16 + jj];

    #pragma unroll 4
    for (int k = 0; k < 64; k++) {
        float a = Al[r * 65 + k];
        const float4* wv = (const float4*)&Wl[k * 64 + q * 16];
        float4 w0 = wv[0], w1 = wv[1], w2 = wv[2], w3 = wv[3];
        acc[0]  += a * w0.x; acc[1]  += a * w0.y; acc[2]  += a * w0.z; acc[3]  += a * w0.w;
        acc[4]  += a * w1.x; acc[5]  += a * w1.y; acc[6]  += a * w1.z; acc[7]  += a * w1.w;
        acc[8]  += a * w2.x; acc[9]  += a * w2.y; acc[10] += a * w2.z; acc[11] += a * w2.w;
        acc[12] += a * w3.x; acc[13] += a * w3.y; acc[14] += a * w3.z; acc[15] += a * w3.w;
    }
    int i = row0 + r;
    if (i < N_NODES) {
        float4* outv = (float4*)&T[(size_t)i * DIM + q * 16];
        outv[0] = make_float4(acc[0],  acc[1],  acc[2],  acc[3]);
        outv[1] = make_float4(acc[4],  acc[5],  acc[6],  acc[7]);
        outv[2] = make_float4(acc[8],  acc[9],  acc[10], acc[11]);
        outv[3] = make_float4(acc[12], acc[13], acc[14], acc[15]);
    }
}

// ---------------- C init: self-loop + conv bias (replaces memset) ----------------
__global__ void k_initC(const float* __restrict__ T, const float* __restrict__ dinv,
                        const float* __restrict__ bias, float* __restrict__ C) {
    int idx = blockIdx.x * blockDim.x + threadIdx.x;  // float4 index
    int total = N_NODES * (DIM / 4);
    for (; idx < total; idx += gridDim.x * blockDim.x) {
        int i = idx >> 4;
        int jq = idx & 15;
        float d = dinv[i];
        float sw = d * d;
        float4 t = ((const float4*)T)[idx];
        float4 bb = ((const float4*)bias)[jq];
        float4 c;
        c.x = t.x * sw + bb.x;
        c.y = t.y * sw + bb.y;
        c.z = t.z * sw + bb.z;
        c.w = t.w * sw + bb.w;
        ((float4*)C)[idx] = c;
    }
}

// ---------------- edge scatter: C[col] += T[row] * dinv[row]*dinv[col] ----------------
// one wave per edge, lane = feature
__global__ void k_scatter(const float* __restrict__ T, const float* __restrict__ dinv,
                          const int* __restrict__ ei, float* __restrict__ C) {
    int lane = threadIdx.x & 63;
    int wid = blockIdx.x * (blockDim.x >> 6) + (threadIdx.x >> 6);
    int nw = gridDim.x * (blockDim.x >> 6);
    for (int e = wid; e < N_EDGES; e += nw) {
        int r = ei[e];
        int c = ei[N_EDGES + e];
        float w = dinv[r] * dinv[c];
        float v = T[(size_t)r * DIM + lane] * w;
        atomicAdd(&C[(size_t)c * DIM + lane], v);
    }
}

// ---------------- mean-pool accumulate (BN applied on the fly) ----------------
__global__ void k_pool(const float* __restrict__ H, const float* __restrict__ scale,
                       const float* __restrict__ shift, const int* __restrict__ batch,
                       float* __restrict__ pool, float* __restrict__ cnt) {
    int j = threadIdx.x & 63, rg = threadIdx.x >> 6;
    for (int i = blockIdx.x * 4 + rg; i < N_NODES; i += gridDim.x * 4) {
        int g = batch[i];
        float v = H[i * DIM + j] * scale[j] + shift[j];
        atomicAdd(&pool[g * DIM + j], v);
        if (j == 0) atomicAdd(&cnt[g], 1.f);
    }
}

// ---------------- final: out[g] = (pool[g]/cnt[g]) @ Wout + bout ----------------
__global__ void k_final(const float* __restrict__ pool, const float* __restrict__ cnt,
                        const float* __restrict__ Wout, const float* __restrict__ bout,
                        float* __restrict__ out) {
    int g = blockIdx.x;
    int l = threadIdx.x;
    float c = fmaxf(cnt[g], 1.f);
    float p = pool[g * DIM + l] / c;
    float a0 = p * Wout[l * 2 + 0];
    float a1 = p * Wout[l * 2 + 1];
    #pragma unroll
    for (int off = 32; off; off >>= 1) {
        a0 += __shfl_down(a0, off, 64);
        a1 += __shfl_down(a1, off, 64);
    }
    if (l == 0) {
        out[g * 2 + 0] = a0 + bout[0];
        out[g * 2 + 1] = a1 + bout[1];
    }
}

extern "C" void kernel_launch(void* const* d_in, const int* in_sizes, int n_in,
                              void* d_out, int out_size, void* d_ws, size_t ws_size,
                              hipStream_t stream) {
    (void)in_sizes; (void)n_in; (void)out_size; (void)ws_size;
    const float* x       = (const float*)d_in[0];
    const int*   ei      = (const int*)d_in[1];
    const int*   batch   = (const int*)d_in[2];
    const float* bn_in_g = (const float*)d_in[3];
    const float* bn_in_b = (const float*)d_in[4];
    const float* W1      = (const float*)d_in[5];
    const float* b1      = (const float*)d_in[6];
    const float* g1      = (const float*)d_in[7];
    const float* be1     = (const float*)d_in[8];
    const float* W2      = (const float*)d_in[9];
    const float* b2      = (const float*)d_in[10];
    const float* g2      = (const float*)d_in[11];
    const float* be2     = (const float*)d_in[12];
    const float* Wout    = (const float*)d_in[13];
    const float* bout    = (const float*)d_in[14];
    float* out = (float*)d_out;

    // workspace layout (~52 MB)
    float* buf0   = (float*)d_ws;
    float* buf1   = buf0 + (size_t)N_NODES * DIM;
    float* dinv   = buf1 + (size_t)N_NODES * DIM;
    int*   degc   = (int*)(dinv + N_NODES);
    float* gsum   = (float*)(degc + N_NODES);
    float* gsumsq = gsum + DIM;
    float* scale  = gsumsq + DIM;
    float* shift  = scale + DIM;
    float* cshift = shift + DIM;
    float* pool   = cshift + DIM;
    float* cnt    = pool + (size_t)N_GRAPHS * DIM;

    // ---- normalization coefficients ----
    hipMemsetAsync(degc, 0, N_NODES * sizeof(int), stream);
    k_deg<<<N_EDGES / 256, 256, 0, stream>>>(ei, degc);
    k_dinv<<<(N_NODES + 255) / 256, 256, 0, stream>>>(degc, dinv);

    // ---- input BN -> GEMM1 -> scatter ----
    hipMemsetAsync(gsum, 0, 2 * DIM * sizeof(float), stream);
    k_stats_x<<<1024, 256, 0, stream>>>(x, gsum, gsumsq);
    k_bnfinal<<<1, 64, 0, stream>>>(gsum, gsumsq, bn_in_g, bn_in_b, scale, shift);
    k_foldbias<<<1, 64, 0, stream>>>(W1, shift, cshift);
    k_gemm<<<(N_NODES + 63) / 64, 256, 0, stream>>>(x, W1, scale, cshift, buf0);      // T1 -> buf0
    k_initC<<<2048, 256, 0, stream>>>(buf0, dinv, b1, buf1);                          // C1 -> buf1
    k_scatter<<<8192, 256, 0, stream>>>(buf0, dinv, ei, buf1);

    // ---- relu + BN1 stats -> GEMM2 -> scatter ----
    hipMemsetAsync(gsum, 0, 2 * DIM * sizeof(float), stream);
    k_stats_relu<<<1024, 256, 0, stream>>>(buf1, buf0, gsum, gsumsq);                 // H1 -> buf0
    k_bnfinal<<<1, 64, 0, stream>>>(gsum, gsumsq, g1, be1, scale, shift);
    k_foldbias<<<1, 64, 0, stream>>>(W2, shift, cshift);
    k_gemm<<<(N_NODES + 63) / 64, 256, 0, stream>>>(buf0, W2, scale, cshift, buf1);   // T2 -> buf1
    k_initC<<<2048, 256, 0, stream>>>(buf1, dinv, b2, buf0);                          // C2 -> buf0
    k_scatter<<<8192, 256, 0, stream>>>(buf1, dinv, ei, buf0);

    // ---- relu + BN2 stats -> pool -> linear ----
    hipMemsetAsync(gsum, 0, 2 * DIM * sizeof(float), stream);
    k_stats_relu<<<1024, 256, 0, stream>>>(buf0, buf1, gsum, gsumsq);                 // H2 -> buf1
    k_bnfinal<<<1, 64, 0, stream>>>(gsum, gsumsq, g2, be2, scale, shift);
    hipMemsetAsync(pool, 0, (N_GRAPHS * DIM + N_GRAPHS) * sizeof(float), stream);
    k_pool<<<1024, 256, 0, stream>>>(buf1, scale, shift, batch, pool, cnt);
    k_final<<<N_GRAPHS, 64, 0, stream>>>(pool, cnt, Wout, bout, out);
}

// Round 2
// 677.358 us; speedup vs baseline: 1.4749x; 1.4749x over previous
//
#include <hip/hip_runtime.h>
#include <math.h>

#define N_NODES 100000
#define N_EDGES 1280000
#define DIM 64
#define N_GRAPHS 1000
#define BN_EPS 1e-5f
#define SCAN_BLOCKS 392   // 392*256 = 100352 >= N_NODES

// ---------------- degree / per-graph count ----------------
__global__ void k_deg(const int* __restrict__ ei, int* __restrict__ degc) {
    int e = blockIdx.x * blockDim.x + threadIdx.x;
    if (e < N_EDGES) atomicAdd(&degc[ei[N_EDGES + e]], 1);
}

__global__ void k_cnt(const int* __restrict__ batch, float* __restrict__ cnt) {
    int i = blockIdx.x * blockDim.x + threadIdx.x;
    if (i < N_NODES) atomicAdd(&cnt[batch[i]], 1.f);
}

__global__ void k_dinv(const int* __restrict__ degc, float* __restrict__ dinv) {
    int i = blockIdx.x * blockDim.x + threadIdx.x;
    if (i < N_NODES) dinv[i] = 1.0f / sqrtf((float)(degc[i] + 1)); // +1 self-loop
}

// ---------------- 3-step exclusive scan of deg -> rowstart ----------------
// s1: per-block inclusive scan (into iscan) + block totals
__global__ void k_scan1(const int* __restrict__ deg, int* __restrict__ iscan,
                        int* __restrict__ bsum) {
    __shared__ int ls[256];
    int i = blockIdx.x * 256 + threadIdx.x;
    int v = (i < N_NODES) ? deg[i] : 0;
    ls[threadIdx.x] = v;
    __syncthreads();
    for (int off = 1; off < 256; off <<= 1) {
        int t = (threadIdx.x >= off) ? ls[threadIdx.x - off] : 0;
        __syncthreads();
        ls[threadIdx.x] += t;
        __syncthreads();
    }
    if (i < N_NODES) iscan[i] = ls[threadIdx.x];
    if (threadIdx.x == 255) bsum[blockIdx.x] = ls[255];
}

// s2: exclusive scan of the 392 block sums (single block)
__global__ void k_scan2(const int* __restrict__ bsum, int* __restrict__ boff) {
    __shared__ int ls[512];
    int t = threadIdx.x;
    int v0 = (t < SCAN_BLOCKS) ? bsum[t] : 0;
    ls[t] = v0;
    __syncthreads();
    for (int off = 1; off < 512; off <<= 1) {
        int v = (t >= off) ? ls[t - off] : 0;
        __syncthreads();
        ls[t] += v;
        __syncthreads();
    }
    if (t < SCAN_BLOCKS) boff[t] = ls[t] - v0;  // exclusive
}

// s3: rowstart[i] = boff[blk] + iscan[i] - deg[i]; cursor = rowstart
__global__ void k_scan3(const int* __restrict__ deg, const int* __restrict__ iscan,
                        const int* __restrict__ boff, int* __restrict__ rowstart,
                        int* __restrict__ cursor) {
    int i = blockIdx.x * 256 + threadIdx.x;
    if (i < N_NODES) {
        int rs = boff[blockIdx.x] + iscan[i] - deg[i];
        rowstart[i] = rs;
        cursor[i] = rs;
    }
    if (i == 0) rowstart[N_NODES] = N_EDGES;
}

// fill CSR (by destination): csr_src[pos]=src, csr_w[pos]=dinv[src]*dinv[dst]
__global__ void k_fill(const int* __restrict__ ei, const float* __restrict__ dinv,
                       int* __restrict__ cursor, int* __restrict__ csr_src,
                       float* __restrict__ csr_w) {
    int e = blockIdx.x * blockDim.x + threadIdx.x;
    if (e < N_EDGES) {
        int r = ei[e], c = ei[N_EDGES + e];
        int pos = atomicAdd(&cursor[c], 1);
        csr_src[pos] = r;
        csr_w[pos] = dinv[r] * dinv[c];
    }
}

// ---------------- input BN statistics ----------------
__global__ void k_stats_x(const float* __restrict__ X,
                          float* __restrict__ gsum, float* __restrict__ gsumsq) {
    int j = threadIdx.x & 63, rg = threadIdx.x >> 6;
    float s = 0.f, s2 = 0.f;
    for (int i = blockIdx.x * 4 + rg; i < N_NODES; i += gridDim.x * 4) {
        float v = X[i * DIM + j];
        s += v; s2 += v * v;
    }
    __shared__ float ls[256], ls2[256];
    ls[threadIdx.x] = s; ls2[threadIdx.x] = s2;
    __syncthreads();
    if (threadIdx.x < 64) {
        s  = ls[j]  + ls[64 + j]  + ls[128 + j]  + ls[192 + j];
        s2 = ls2[j] + ls2[64 + j] + ls2[128 + j] + ls2[192 + j];
        atomicAdd(&gsum[j], s);
        atomicAdd(&gsumsq[j], s2);
    }
}

// scale = g*rsqrt(var+eps); shift = b - mean*scale
__global__ void k_bnfinal(const float* __restrict__ gsum, const float* __restrict__ gsumsq,
                          const float* __restrict__ g, const float* __restrict__ b,
                          float* __restrict__ scale, float* __restrict__ shift) {
    int j = threadIdx.x;
    float mean = gsum[j] * (1.0f / N_NODES);
    float var  = gsumsq[j] * (1.0f / N_NODES) - mean * mean;
    float inv  = 1.0f / sqrtf(var + BN_EPS);
    float sc   = g[j] * inv;
    scale[j] = sc;
    shift[j] = b[j] - mean * sc;
}

// cshift[j] = sum_k shift[k] * W[k][j]
__global__ void k_foldbias(const float* __restrict__ W, const float* __restrict__ shift,
                           float* __restrict__ cshift) {
    int j = threadIdx.x;
    float s = 0.f;
    for (int k = 0; k < DIM; k++) s += shift[k] * W[k * DIM + j];
    cshift[j] = s;
}

// ---------------- GEMM: T = (X*scale) @ W + cshift ----------------
__global__ __launch_bounds__(256) void k_gemm(const float* __restrict__ X,
                                              const float* __restrict__ W,
                                              const float* __restrict__ scale,
                                              const float* __restrict__ cshift,
                                              float* __restrict__ T) {
    __shared__ float Wl[64 * 64];
    __shared__ float Al[64 * 65];
    for (int t = threadIdx.x; t < 4096; t += 256) {
        int k = t >> 6;
        Wl[t] = W[t] * scale[k];
    }
    int row0 = blockIdx.x * 64;
    for (int t = threadIdx.x; t < 4096; t += 256) {
        int r = t >> 6, k = t & 63;
        int i = row0 + r;
        Al[r * 65 + k] = (i < N_NODES) ? X[i * DIM + k] : 0.f;
    }
    __syncthreads();

    int r = threadIdx.x & 63;
    int q = threadIdx.x >> 6;
    float acc[16];
    #pragma unroll
    for (int jj = 0; jj < 16; jj++) acc[jj] = cshift[q * 16 + jj];

    #pragma unroll 4
    for (int k = 0; k < 64; k++) {
        float a = Al[r * 65 + k];
        const float4* wv = (const float4*)&Wl[k * 64 + q * 16];
        float4 w0 = wv[0], w1 = wv[1], w2 = wv[2], w3 = wv[3];
        acc[0]  += a * w0.x; acc[1]  += a * w0.y; acc[2]  += a * w0.z; acc[3]  += a * w0.w;
        acc[4]  += a * w1.x; acc[5]  += a * w1.y; acc[6]  += a * w1.z; acc[7]  += a * w1.w;
        acc[8]  += a * w2.x; acc[9]  += a * w2.y; acc[10] += a * w2.z; acc[11] += a * w2.w;
        acc[12] += a * w3.x; acc[13] += a * w3.y; acc[14] += a * w3.z; acc[15] += a * w3.w;
    }
    int i = row0 + r;
    if (i < N_NODES) {
        float4* outv = (float4*)&T[(size_t)i * DIM + q * 16];
        outv[0] = make_float4(acc[0],  acc[1],  acc[2],  acc[3]);
        outv[1] = make_float4(acc[4],  acc[5],  acc[6],  acc[7]);
        outv[2] = make_float4(acc[8],  acc[9],  acc[10], acc[11]);
        outv[3] = make_float4(acc[12], acc[13], acc[14], acc[15]);
    }
}

// ---------------- gather conv layer 1: H = relu(agg + bias), + BN stats ----------------
// one wave per dst node (contiguous chunk per wave), lane = feature
__global__ __launch_bounds__(256) void k_gather1(const float* __restrict__ T,
                                                 const float* __restrict__ dinv,
                                                 const int* __restrict__ rowstart,
                                                 const int* __restrict__ csr_src,
                                                 const float* __restrict__ csr_w,
                                                 const float* __restrict__ bias,
                                                 float* __restrict__ H,
                                                 float* __restrict__ gsum,
                                                 float* __restrict__ gsumsq) {
    int lane = threadIdx.x & 63;
    int wid = blockIdx.x * 4 + (threadIdx.x >> 6);
    int nw = gridDim.x * 4;
    int per = (N_NODES + nw - 1) / nw;
    int i0 = wid * per;
    int i1 = min(i0 + per, N_NODES);
    float s = 0.f, s2 = 0.f;
    for (int i = i0; i < i1; i++) {
        float di = dinv[i];
        float acc = T[(size_t)i * DIM + lane] * (di * di);  // self-loop
        int e0 = rowstart[i], e1 = rowstart[i + 1];
        for (int eb = e0; eb < e1; eb += 64) {
            int idx = eb + lane;
            int sl = 0; float wl = 0.f;
            if (idx < e1) { sl = csr_src[idx]; wl = csr_w[idx]; }
            int n = min(64, e1 - eb);
            for (int t = 0; t < n; t++) {
                int sv = __shfl(sl, t, 64);
                float w = __shfl(wl, t, 64);
                acc += T[(size_t)sv * DIM + lane] * w;
            }
        }
        float h = fmaxf(acc + bias[lane], 0.f);
        H[(size_t)i * DIM + lane] = h;
        s += h; s2 += h * h;
    }
    __shared__ float ls[256], ls2[256];
    ls[threadIdx.x] = s; ls2[threadIdx.x] = s2;
    __syncthreads();
    if (threadIdx.x < 64) {
        s  = ls[lane]  + ls[64 + lane]  + ls[128 + lane]  + ls[192 + lane];
        s2 = ls2[lane] + ls2[64 + lane] + ls2[128 + lane] + ls2[192 + lane];
        atomicAdd(&gsum[lane], s);
        atomicAdd(&gsumsq[lane], s2);
    }
}

// ---------------- gather conv layer 2: relu -> pool + BN stats (H2 never stored) ----------------
__global__ __launch_bounds__(256) void k_gather2(const float* __restrict__ T,
                                                 const float* __restrict__ dinv,
                                                 const int* __restrict__ rowstart,
                                                 const int* __restrict__ csr_src,
                                                 const float* __restrict__ csr_w,
                                                 const float* __restrict__ bias,
                                                 const int* __restrict__ batch,
                                                 float* __restrict__ pool,
                                                 float* __restrict__ gsum,
                                                 float* __restrict__ gsumsq) {
    int lane = threadIdx.x & 63;
    int wid = blockIdx.x * 4 + (threadIdx.x >> 6);
    int nw = gridDim.x * 4;
    int per = (N_NODES + nw - 1) / nw;
    int i0 = wid * per;
    int i1 = min(i0 + per, N_NODES);
    float s = 0.f, s2 = 0.f;
    float ps = 0.f;
    int cur_g = -1;
    for (int i = i0; i < i1; i++) {
        float di = dinv[i];
        float acc = T[(size_t)i * DIM + lane] * (di * di);
        int e0 = rowstart[i], e1 = rowstart[i + 1];
        for (int eb = e0; eb < e1; eb += 64) {
            int idx = eb + lane;
            int sl = 0; float wl = 0.f;
            if (idx < e1) { sl = csr_src[idx]; wl = csr_w[idx]; }
            int n = min(64, e1 - eb);
            for (int t = 0; t < n; t++) {
                int sv = __shfl(sl, t, 64);
                float w = __shfl(wl, t, 64);
                acc += T[(size_t)sv * DIM + lane] * w;
            }
        }
        float h = fmaxf(acc + bias[lane], 0.f);
        s += h; s2 += h * h;
        int g = batch[i];                      // sorted -> rarely changes within chunk
        if (g != cur_g) {
            if (cur_g >= 0) atomicAdd(&pool[(size_t)cur_g * DIM + lane], ps);
            ps = 0.f; cur_g = g;
        }
        ps += h;
    }
    if (cur_g >= 0) atomicAdd(&pool[(size_t)cur_g * DIM + lane], ps);
    __shared__ float ls[256], ls2[256];
    ls[threadIdx.x] = s; ls2[threadIdx.x] = s2;
    __syncthreads();
    if (threadIdx.x < 64) {
        s  = ls[lane]  + ls[64 + lane]  + ls[128 + lane]  + ls[192 + lane];
        s2 = ls2[lane] + ls2[64 + lane] + ls2[128 + lane] + ls2[192 + lane];
        atomicAdd(&gsum[lane], s);
        atomicAdd(&gsumsq[lane], s2);
    }
}

// ---------------- final: out[g] = ((pool/cnt)*scale + shift) @ Wout + bout ----------------
__global__ void k_final(const float* __restrict__ pool, const float* __restrict__ cnt,
                        const float* __restrict__ scale, const float* __restrict__ shift,
                        const float* __restrict__ Wout, const float* __restrict__ bout,
                        float* __restrict__ out) {
    int g = blockIdx.x;
    int l = threadIdx.x;
    float c = fmaxf(cnt[g], 1.f);
    float p = (pool[g * DIM + l] / c) * scale[l] + shift[l];
    float a0 = p * Wout[l * 2 + 0];
    float a1 = p * Wout[l * 2 + 1];
    #pragma unroll
    for (int off = 32; off; off >>= 1) {
        a0 += __shfl_down(a0, off, 64);
        a1 += __shfl_down(a1, off, 64);
    }
    if (l == 0) {
        out[g * 2 + 0] = a0 + bout[0];
        out[g * 2 + 1] = a1 + bout[1];
    }
}

extern "C" void kernel_launch(void* const* d_in, const int* in_sizes, int n_in,
                              void* d_out, int out_size, void* d_ws, size_t ws_size,
                              hipStream_t stream) {
    (void)in_sizes; (void)n_in; (void)out_size; (void)ws_size;
    const float* x       = (const float*)d_in[0];
    const int*   ei      = (const int*)d_in[1];
    const int*   batch   = (const int*)d_in[2];
    const float* bn_in_g = (const float*)d_in[3];
    const float* bn_in_b = (const float*)d_in[4];
    const float* W1      = (const float*)d_in[5];
    const float* b1      = (const float*)d_in[6];
    const float* g1      = (const float*)d_in[7];
    const float* be1     = (const float*)d_in[8];
    const float* W2      = (const float*)d_in[9];
    const float* b2      = (const float*)d_in[10];
    const float* g2      = (const float*)d_in[11];
    const float* be2     = (const float*)d_in[12];
    const float* Wout    = (const float*)d_in[13];
    const float* bout    = (const float*)d_in[14];
    float* out = (float*)d_out;

    // workspace layout (~64 MB)
    float* buf0     = (float*)d_ws;                          // 25.6 MB
    float* buf1     = buf0 + (size_t)N_NODES * DIM;          // 25.6 MB
    float* dinv     = buf1 + (size_t)N_NODES * DIM;          // 400 KB
    int*   degc     = (int*)(dinv + N_NODES);                // 400 KB
    int*   iscan    = degc + N_NODES;                        // 400 KB
    int*   rowstart = iscan + N_NODES;                       // 400 KB + 4
    int*   cursor   = rowstart + N_NODES + 1;                // 400 KB
    int*   csr_src  = cursor + N_NODES;                      // 5.12 MB
    float* csr_w    = (float*)(csr_src + N_EDGES);           // 5.12 MB
    int*   bsum     = (int*)(csr_w + N_EDGES);               // ~1.6 KB
    int*   boff     = bsum + SCAN_BLOCKS;                    // ~1.6 KB
    float* gsum     = (float*)(boff + SCAN_BLOCKS);
    float* gsumsq   = gsum + DIM;
    float* scale    = gsumsq + DIM;
    float* shift    = scale + DIM;
    float* cshift   = shift + DIM;
    float* pool     = cshift + DIM;                          // 256 KB
    float* cnt      = pool + (size_t)N_GRAPHS * DIM;         // 4 KB

    // ---- CSR build + norm coefficients ----
    hipMemsetAsync(degc, 0, N_NODES * sizeof(int), stream);
    hipMemsetAsync(pool, 0, (N_GRAPHS * DIM + N_GRAPHS) * sizeof(float), stream);
    k_deg<<<N_EDGES / 256, 256, 0, stream>>>(ei, degc);
    k_cnt<<<(N_NODES + 255) / 256, 256, 0, stream>>>(batch, cnt);
    k_dinv<<<(N_NODES + 255) / 256, 256, 0, stream>>>(degc, dinv);
    k_scan1<<<SCAN_BLOCKS, 256, 0, stream>>>(degc, iscan, bsum);
    k_scan2<<<1, 512, 0, stream>>>(bsum, boff);
    k_scan3<<<SCAN_BLOCKS, 256, 0, stream>>>(degc, iscan, boff, rowstart, cursor);
    k_fill<<<N_EDGES / 256, 256, 0, stream>>>(ei, dinv, cursor, csr_src, csr_w);

    // ---- input BN -> GEMM1 -> gather1 (fused bias+relu+stats) ----
    hipMemsetAsync(gsum, 0, 2 * DIM * sizeof(float), stream);
    k_stats_x<<<1024, 256, 0, stream>>>(x, gsum, gsumsq);
    k_bnfinal<<<1, 64, 0, stream>>>(gsum, gsumsq, bn_in_g, bn_in_b, scale, shift);
    k_foldbias<<<1, 64, 0, stream>>>(W1, shift, cshift);
    k_gemm<<<(N_NODES + 63) / 64, 256, 0, stream>>>(x, W1, scale, cshift, buf0);   // T1
    hipMemsetAsync(gsum, 0, 2 * DIM * sizeof(float), stream);
    k_gather1<<<2048, 256, 0, stream>>>(buf0, dinv, rowstart, csr_src, csr_w, b1,
                                        buf1, gsum, gsumsq);                       // H1

    // ---- BN1 -> GEMM2 -> gather2 (fused bias+relu+stats+pool) ----
    k_bnfinal<<<1, 64, 0, stream>>>(gsum, gsumsq, g1, be1, scale, shift);
    k_foldbias<<<1, 64, 0, stream>>>(W2, shift, cshift);
    k_gemm<<<(N_NODES + 63) / 64, 256, 0, stream>>>(buf1, W2, scale, cshift, buf0); // T2
    hipMemsetAsync(gsum, 0, 2 * DIM * sizeof(float), stream);
    k_gather2<<<2048, 256, 0, stream>>>(buf0, dinv, rowstart, csr_src, csr_w, b2,
                                        batch, pool, gsum, gsumsq);

    // ---- BN2 (applied post-pool; BN is affine, pool is linear) -> linear ----
    k_bnfinal<<<1, 64, 0, stream>>>(gsum, gsumsq, g2, be2, scale, shift);
    k_final<<<N_GRAPHS, 64, 0, stream>>>(pool, cnt, scale, shift, Wout, bout, out);
}

// Round 3
// 630.579 us; speedup vs baseline: 1.5843x; 1.0742x over previous
//
#include <hip/hip_runtime.h>
#include <math.h>

#define N_NODES 100000
#define N_EDGES 1280000
#define DIM 64
#define N_GRAPHS 1000
#define BN_EPS 1e-5f
#define SCAN_BLOCKS 392   // 392*256 = 100352 >= N_NODES

// ---------------- degree / per-graph count ----------------
__global__ void k_deg(const int* __restrict__ ei, int* __restrict__ degc) {
    int e = blockIdx.x * blockDim.x + threadIdx.x;
    if (e < N_EDGES) atomicAdd(&degc[ei[N_EDGES + e]], 1);
}

__global__ void k_cnt(const int* __restrict__ batch, float* __restrict__ cnt) {
    int i = blockIdx.x * blockDim.x + threadIdx.x;
    if (i < N_NODES) atomicAdd(&cnt[batch[i]], 1.f);
}

__global__ void k_dinv(const int* __restrict__ degc, float* __restrict__ dinv) {
    int i = blockIdx.x * blockDim.x + threadIdx.x;
    if (i < N_NODES) dinv[i] = 1.0f / sqrtf((float)(degc[i] + 1)); // +1 self-loop
}

// ---------------- 3-step exclusive scan of deg -> rowstart ----------------
__global__ void k_scan1(const int* __restrict__ deg, int* __restrict__ iscan,
                        int* __restrict__ bsum) {
    __shared__ int ls[256];
    int i = blockIdx.x * 256 + threadIdx.x;
    int v = (i < N_NODES) ? deg[i] : 0;
    ls[threadIdx.x] = v;
    __syncthreads();
    for (int off = 1; off < 256; off <<= 1) {
        int t = (threadIdx.x >= off) ? ls[threadIdx.x - off] : 0;
        __syncthreads();
        ls[threadIdx.x] += t;
        __syncthreads();
    }
    if (i < N_NODES) iscan[i] = ls[threadIdx.x];
    if (threadIdx.x == 255) bsum[blockIdx.x] = ls[255];
}

__global__ void k_scan2(const int* __restrict__ bsum, int* __restrict__ boff) {
    __shared__ int ls[512];
    int t = threadIdx.x;
    int v0 = (t < SCAN_BLOCKS) ? bsum[t] : 0;
    ls[t] = v0;
    __syncthreads();
    for (int off = 1; off < 512; off <<= 1) {
        int v = (t >= off) ? ls[t - off] : 0;
        __syncthreads();
        ls[t] += v;
        __syncthreads();
    }
    if (t < SCAN_BLOCKS) boff[t] = ls[t] - v0;  // exclusive
}

__global__ void k_scan3(const int* __restrict__ deg, const int* __restrict__ iscan,
                        const int* __restrict__ boff, int* __restrict__ rowstart,
                        int* __restrict__ cursor) {
    int i = blockIdx.x * 256 + threadIdx.x;
    if (i < N_NODES) {
        int rs = boff[blockIdx.x] + iscan[i] - deg[i];
        rowstart[i] = rs;
        cursor[i] = rs;
    }
    if (i == 0) rowstart[N_NODES] = N_EDGES;
}

// fill CSR (by destination): csr_src[pos]=src, csr_w[pos]=dinv[src]*dinv[dst]
__global__ void k_fill(const int* __restrict__ ei, const float* __restrict__ dinv,
                       int* __restrict__ cursor, int* __restrict__ csr_src,
                       float* __restrict__ csr_w) {
    int e = blockIdx.x * blockDim.x + threadIdx.x;
    if (e < N_EDGES) {
        int r = ei[e], c = ei[N_EDGES + e];
        int pos = atomicAdd(&cursor[c], 1);
        csr_src[pos] = r;
        csr_w[pos] = dinv[r] * dinv[c];
    }
}

// ---------------- input BN statistics ----------------
__global__ void k_stats_x(const float* __restrict__ X,
                          float* __restrict__ gsum, float* __restrict__ gsumsq) {
    int j = threadIdx.x & 63, rg = threadIdx.x >> 6;
    float s = 0.f, s2 = 0.f;
    for (int i = blockIdx.x * 4 + rg; i < N_NODES; i += gridDim.x * 4) {
        float v = X[i * DIM + j];
        s += v; s2 += v * v;
    }
    __shared__ float ls[256], ls2[256];
    ls[threadIdx.x] = s; ls2[threadIdx.x] = s2;
    __syncthreads();
    if (threadIdx.x < 64) {
        s  = ls[j]  + ls[64 + j]  + ls[128 + j]  + ls[192 + j];
        s2 = ls2[j] + ls2[64 + j] + ls2[128 + j] + ls2[192 + j];
        atomicAdd(&gsum[j], s);
        atomicAdd(&gsumsq[j], s2);
    }
}

// scale = g*rsqrt(var+eps); shift = b - mean*scale
__global__ void k_bnfinal(const float* __restrict__ gsum, const float* __restrict__ gsumsq,
                          const float* __restrict__ g, const float* __restrict__ b,
                          float* __restrict__ scale, float* __restrict__ shift) {
    int j = threadIdx.x;
    float mean = gsum[j] * (1.0f / N_NODES);
    float var  = gsumsq[j] * (1.0f / N_NODES) - mean * mean;
    float inv  = 1.0f / sqrtf(var + BN_EPS);
    float sc   = g[j] * inv;
    scale[j] = sc;
    shift[j] = b[j] - mean * sc;
}

// cshift[j] = sum_k shift[k] * W[k][j]
__global__ void k_foldbias(const float* __restrict__ W, const float* __restrict__ shift,
                           float* __restrict__ cshift) {
    int j = threadIdx.x;
    float s = 0.f;
    for (int k = 0; k < DIM; k++) s += shift[k] * W[k * DIM + j];
    cshift[j] = s;
}

// ---------------- GEMM: T = (X*scale) @ W + cshift ----------------
__global__ __launch_bounds__(256) void k_gemm(const float* __restrict__ X,
                                              const float* __restrict__ W,
                                              const float* __restrict__ scale,
                                              const float* __restrict__ cshift,
                                              float* __restrict__ T) {
    __shared__ float Wl[64 * 64];
    __shared__ float Al[64 * 65];
    for (int t = threadIdx.x; t < 4096; t += 256) {
        int k = t >> 6;
        Wl[t] = W[t] * scale[k];
    }
    int row0 = blockIdx.x * 64;
    for (int t = threadIdx.x; t < 4096; t += 256) {
        int r = t >> 6, k = t & 63;
        int i = row0 + r;
        Al[r * 65 + k] = (i < N_NODES) ? X[i * DIM + k] : 0.f;
    }
    __syncthreads();

    int r = threadIdx.x & 63;
    int q = threadIdx.x >> 6;
    float acc[16];
    #pragma unroll
    for (int jj = 0; jj < 16; jj++) acc[jj] = cshift[q * 16 + jj];

    #pragma unroll 4
    for (int k = 0; k < 64; k++) {
        float a = Al[r * 65 + k];
        const float4* wv = (const float4*)&Wl[k * 64 + q * 16];
        float4 w0 = wv[0], w1 = wv[1], w2 = wv[2], w3 = wv[3];
        acc[0]  += a * w0.x; acc[1]  += a * w0.y; acc[2]  += a * w0.z; acc[3]  += a * w0.w;
        acc[4]  += a * w1.x; acc[5]  += a * w1.y; acc[6]  += a * w1.z; acc[7]  += a * w1.w;
        acc[8]  += a * w2.x; acc[9]  += a * w2.y; acc[10] += a * w2.z; acc[11] += a * w2.w;
        acc[12] += a * w3.x; acc[13] += a * w3.y; acc[14] += a * w3.z; acc[15] += a * w3.w;
    }
    int i = row0 + r;
    if (i < N_NODES) {
        float4* outv = (float4*)&T[(size_t)i * DIM + q * 16];
        outv[0] = make_float4(acc[0],  acc[1],  acc[2],  acc[3]);
        outv[1] = make_float4(acc[4],  acc[5],  acc[6],  acc[7]);
        outv[2] = make_float4(acc[8],  acc[9],  acc[10], acc[11]);
        outv[3] = make_float4(acc[12], acc[13], acc[14], acc[15]);
    }
}

// ---------------- gather conv layer 1 ----------------
// wave = 4 edge-slots x 16 lanes; lane handles features 4*fq..4*fq+3 as float4.
// 4 independent 256B gathers in flight per trip; no shfl in the load path.
__global__ __launch_bounds__(256) void k_gather1(const float* __restrict__ T,
                                                 const float* __restrict__ dinv,
                                                 const int* __restrict__ rowstart,
                                                 const int* __restrict__ csr_src,
                                                 const float* __restrict__ csr_w,
                                                 const float* __restrict__ bias,
                                                 float* __restrict__ H,
                                                 float* __restrict__ gsum,
                                                 float* __restrict__ gsumsq) {
    int lane = threadIdx.x & 63;
    int sub  = lane >> 4;        // edge slot 0..3
    int fq   = lane & 15;        // float4 feature group
    int wv   = threadIdx.x >> 6;
    int wid = blockIdx.x * 4 + wv;
    int nw = gridDim.x * 4;
    int per = (N_NODES + nw - 1) / nw;
    int i0 = wid * per;
    int i1 = min(i0 + per, N_NODES);
    const float4* T4 = (const float4*)T;
    float4 bb = ((const float4*)bias)[fq];
    float4 s4  = make_float4(0.f, 0.f, 0.f, 0.f);
    float4 s24 = make_float4(0.f, 0.f, 0.f, 0.f);
    for (int i = i0; i < i1; i++) {
        int e0 = rowstart[i], e1 = rowstart[i + 1];
        float4 acc = make_float4(0.f, 0.f, 0.f, 0.f);
        for (int eb = e0 + sub; eb < e1; eb += 4) {
            int src = csr_src[eb];           // broadcast across 16 lanes
            float w = csr_w[eb];
            float4 t = T4[(size_t)src * 16 + fq];
            acc.x += t.x * w; acc.y += t.y * w; acc.z += t.z * w; acc.w += t.w * w;
        }
        // reduce the 4 edge slots
        acc.x += __shfl_xor(acc.x, 16, 64); acc.y += __shfl_xor(acc.y, 16, 64);
        acc.z += __shfl_xor(acc.z, 16, 64); acc.w += __shfl_xor(acc.w, 16, 64);
        acc.x += __shfl_xor(acc.x, 32, 64); acc.y += __shfl_xor(acc.y, 32, 64);
        acc.z += __shfl_xor(acc.z, 32, 64); acc.w += __shfl_xor(acc.w, 32, 64);
        // self-loop + bias + relu
        float di = dinv[i];
        float sw = di * di;
        float4 ts = T4[(size_t)i * 16 + fq];
        float4 h;
        h.x = fmaxf(acc.x + ts.x * sw + bb.x, 0.f);
        h.y = fmaxf(acc.y + ts.y * sw + bb.y, 0.f);
        h.z = fmaxf(acc.z + ts.z * sw + bb.z, 0.f);
        h.w = fmaxf(acc.w + ts.w * sw + bb.w, 0.f);
        if (sub == 0) {
            ((float4*)H)[(size_t)i * 16 + fq] = h;
            s4.x += h.x; s4.y += h.y; s4.z += h.z; s4.w += h.w;
            s24.x += h.x * h.x; s24.y += h.y * h.y; s24.z += h.z * h.z; s24.w += h.w * h.w;
        }
    }
    __shared__ float ls[4 * 64], ls2[4 * 64];
    if (sub == 0) {
        ls[wv * 64 + 4 * fq + 0] = s4.x;  ls2[wv * 64 + 4 * fq + 0] = s24.x;
        ls[wv * 64 + 4 * fq + 1] = s4.y;  ls2[wv * 64 + 4 * fq + 1] = s24.y;
        ls[wv * 64 + 4 * fq + 2] = s4.z;  ls2[wv * 64 + 4 * fq + 2] = s24.z;
        ls[wv * 64 + 4 * fq + 3] = s4.w;  ls2[wv * 64 + 4 * fq + 3] = s24.w;
    }
    __syncthreads();
    if (threadIdx.x < 64) {
        int j = threadIdx.x;
        float s  = ls[j]  + ls[64 + j]  + ls[128 + j]  + ls[192 + j];
        float s2 = ls2[j] + ls2[64 + j] + ls2[128 + j] + ls2[192 + j];
        atomicAdd(&gsum[j], s);
        atomicAdd(&gsumsq[j], s2);
    }
}

// ---------------- gather conv layer 2: relu -> pool + BN stats (H2 never stored) ----------------
__global__ __launch_bounds__(256) void k_gather2(const float* __restrict__ T,
                                                 const float* __restrict__ dinv,
                                                 const int* __restrict__ rowstart,
                                                 const int* __restrict__ csr_src,
                                                 const float* __restrict__ csr_w,
                                                 const float* __restrict__ bias,
                                                 const int* __restrict__ batch,
                                                 float* __restrict__ pool,
                                                 float* __restrict__ gsum,
                                                 float* __restrict__ gsumsq) {
    int lane = threadIdx.x & 63;
    int sub  = lane >> 4;
    int fq   = lane & 15;
    int wv   = threadIdx.x >> 6;
    int wid = blockIdx.x * 4 + wv;
    int nw = gridDim.x * 4;
    int per = (N_NODES + nw - 1) / nw;
    int i0 = wid * per;
    int i1 = min(i0 + per, N_NODES);
    const float4* T4 = (const float4*)T;
    float4 bb = ((const float4*)bias)[fq];
    float4 s4  = make_float4(0.f, 0.f, 0.f, 0.f);
    float4 s24 = make_float4(0.f, 0.f, 0.f, 0.f);
    float4 ps  = make_float4(0.f, 0.f, 0.f, 0.f);
    int cur_g = -1;
    for (int i = i0; i < i1; i++) {
        int e0 = rowstart[i], e1 = rowstart[i + 1];
        float4 acc = make_float4(0.f, 0.f, 0.f, 0.f);
        for (int eb = e0 + sub; eb < e1; eb += 4) {
            int src = csr_src[eb];
            float w = csr_w[eb];
            float4 t = T4[(size_t)src * 16 + fq];
            acc.x += t.x * w; acc.y += t.y * w; acc.z += t.z * w; acc.w += t.w * w;
        }
        acc.x += __shfl_xor(acc.x, 16, 64); acc.y += __shfl_xor(acc.y, 16, 64);
        acc.z += __shfl_xor(acc.z, 16, 64); acc.w += __shfl_xor(acc.w, 16, 64);
        acc.x += __shfl_xor(acc.x, 32, 64); acc.y += __shfl_xor(acc.y, 32, 64);
        acc.z += __shfl_xor(acc.z, 32, 64); acc.w += __shfl_xor(acc.w, 32, 64);
        float di = dinv[i];
        float sw = di * di;
        float4 ts = T4[(size_t)i * 16 + fq];
        float4 h;
        h.x = fmaxf(acc.x + ts.x * sw + bb.x, 0.f);
        h.y = fmaxf(acc.y + ts.y * sw + bb.y, 0.f);
        h.z = fmaxf(acc.z + ts.z * sw + bb.z, 0.f);
        h.w = fmaxf(acc.w + ts.w * sw + bb.w, 0.f);
        if (sub == 0) {
            s4.x += h.x; s4.y += h.y; s4.z += h.z; s4.w += h.w;
            s24.x += h.x * h.x; s24.y += h.y * h.y; s24.z += h.z * h.z; s24.w += h.w * h.w;
            int g = batch[i];                  // sorted -> rarely changes
            if (g != cur_g) {
                if (cur_g >= 0) {
                    atomicAdd(&pool[(size_t)cur_g * DIM + 4 * fq + 0], ps.x);
                    atomicAdd(&pool[(size_t)cur_g * DIM + 4 * fq + 1], ps.y);
                    atomicAdd(&pool[(size_t)cur_g * DIM + 4 * fq + 2], ps.z);
                    atomicAdd(&pool[(size_t)cur_g * DIM + 4 * fq + 3], ps.w);
                }
                ps = make_float4(0.f, 0.f, 0.f, 0.f);
                cur_g = g;
            }
            ps.x += h.x; ps.y += h.y; ps.z += h.z; ps.w += h.w;
        }
    }
    if (sub == 0 && cur_g >= 0) {
        atomicAdd(&pool[(size_t)cur_g * DIM + 4 * fq + 0], ps.x);
        atomicAdd(&pool[(size_t)cur_g * DIM + 4 * fq + 1], ps.y);
        atomicAdd(&pool[(size_t)cur_g * DIM + 4 * fq + 2], ps.z);
        atomicAdd(&pool[(size_t)cur_g * DIM + 4 * fq + 3], ps.w);
    }
    __shared__ float ls[4 * 64], ls2[4 * 64];
    if (sub == 0) {
        ls[wv * 64 + 4 * fq + 0] = s4.x;  ls2[wv * 64 + 4 * fq + 0] = s24.x;
        ls[wv * 64 + 4 * fq + 1] = s4.y;  ls2[wv * 64 + 4 * fq + 1] = s24.y;
        ls[wv * 64 + 4 * fq + 2] = s4.z;  ls2[wv * 64 + 4 * fq + 2] = s24.z;
        ls[wv * 64 + 4 * fq + 3] = s4.w;  ls2[wv * 64 + 4 * fq + 3] = s24.w;
    }
    __syncthreads();
    if (threadIdx.x < 64) {
        int j = threadIdx.x;
        float s  = ls[j]  + ls[64 + j]  + ls[128 + j]  + ls[192 + j];
        float s2 = ls2[j] + ls2[64 + j] + ls2[128 + j] + ls2[192 + j];
        atomicAdd(&gsum[j], s);
        atomicAdd(&gsumsq[j], s2);
    }
}

// ---------------- final: out[g] = ((pool/cnt)*scale + shift) @ Wout + bout ----------------
__global__ void k_final(const float* __restrict__ pool, const float* __restrict__ cnt,
                        const float* __restrict__ scale, const float* __restrict__ shift,
                        const float* __restrict__ Wout, const float* __restrict__ bout,
                        float* __restrict__ out) {
    int g = blockIdx.x;
    int l = threadIdx.x;
    float c = fmaxf(cnt[g], 1.f);
    float p = (pool[g * DIM + l] / c) * scale[l] + shift[l];
    float a0 = p * Wout[l * 2 + 0];
    float a1 = p * Wout[l * 2 + 1];
    #pragma unroll
    for (int off = 32; off; off >>= 1) {
        a0 += __shfl_down(a0, off, 64);
        a1 += __shfl_down(a1, off, 64);
    }
    if (l == 0) {
        out[g * 2 + 0] = a0 + bout[0];
        out[g * 2 + 1] = a1 + bout[1];
    }
}

extern "C" void kernel_launch(void* const* d_in, const int* in_sizes, int n_in,
                              void* d_out, int out_size, void* d_ws, size_t ws_size,
                              hipStream_t stream) {
    (void)in_sizes; (void)n_in; (void)out_size; (void)ws_size;
    const float* x       = (const float*)d_in[0];
    const int*   ei      = (const int*)d_in[1];
    const int*   batch   = (const int*)d_in[2];
    const float* bn_in_g = (const float*)d_in[3];
    const float* bn_in_b = (const float*)d_in[4];
    const float* W1      = (const float*)d_in[5];
    const float* b1      = (const float*)d_in[6];
    const float* g1      = (const float*)d_in[7];
    const float* be1     = (const float*)d_in[8];
    const float* W2      = (const float*)d_in[9];
    const float* b2      = (const float*)d_in[10];
    const float* g2      = (const float*)d_in[11];
    const float* be2     = (const float*)d_in[12];
    const float* Wout    = (const float*)d_in[13];
    const float* bout    = (const float*)d_in[14];
    float* out = (float*)d_out;

    // workspace layout (~64 MB)
    float* buf0     = (float*)d_ws;                          // 25.6 MB
    float* buf1     = buf0 + (size_t)N_NODES * DIM;          // 25.6 MB
    float* dinv     = buf1 + (size_t)N_NODES * DIM;          // 400 KB
    int*   degc     = (int*)(dinv + N_NODES);                // 400 KB
    int*   iscan    = degc + N_NODES;                        // 400 KB
    int*   rowstart = iscan + N_NODES;                       // 400 KB + 4
    int*   cursor   = rowstart + N_NODES + 1;                // 400 KB
    int*   csr_src  = cursor + N_NODES;                      // 5.12 MB
    float* csr_w    = (float*)(csr_src + N_EDGES);           // 5.12 MB
    int*   bsum     = (int*)(csr_w + N_EDGES);               // ~1.6 KB
    int*   boff     = bsum + SCAN_BLOCKS;                    // ~1.6 KB
    float* gsum     = (float*)(boff + SCAN_BLOCKS);
    float* gsumsq   = gsum + DIM;
    float* scale    = gsumsq + DIM;
    float* shift    = scale + DIM;
    float* cshift   = shift + DIM;
    float* pool     = cshift + DIM;                          // 256 KB
    float* cnt      = pool + (size_t)N_GRAPHS * DIM;         // 4 KB

    // ---- CSR build + norm coefficients ----
    hipMemsetAsync(degc, 0, N_NODES * sizeof(int), stream);
    hipMemsetAsync(pool, 0, (N_GRAPHS * DIM + N_GRAPHS) * sizeof(float), stream);
    k_deg<<<N_EDGES / 256, 256, 0, stream>>>(ei, degc);
    k_cnt<<<(N_NODES + 255) / 256, 256, 0, stream>>>(batch, cnt);
    k_dinv<<<(N_NODES + 255) / 256, 256, 0, stream>>>(degc, dinv);
    k_scan1<<<SCAN_BLOCKS, 256, 0, stream>>>(degc, iscan, bsum);
    k_scan2<<<1, 512, 0, stream>>>(bsum, boff);
    k_scan3<<<SCAN_BLOCKS, 256, 0, stream>>>(degc, iscan, boff, rowstart, cursor);
    k_fill<<<N_EDGES / 256, 256, 0, stream>>>(ei, dinv, cursor, csr_src, csr_w);

    // ---- input BN -> GEMM1 -> gather1 (fused bias+relu+stats) ----
    hipMemsetAsync(gsum, 0, 2 * DIM * sizeof(float), stream);
    k_stats_x<<<1024, 256, 0, stream>>>(x, gsum, gsumsq);
    k_bnfinal<<<1, 64, 0, stream>>>(gsum, gsumsq, bn_in_g, bn_in_b, scale, shift);
    k_foldbias<<<1, 64, 0, stream>>>(W1, shift, cshift);
    k_gemm<<<(N_NODES + 63) / 64, 256, 0, stream>>>(x, W1, scale, cshift, buf0);   // T1
    hipMemsetAsync(gsum, 0, 2 * DIM * sizeof(float), stream);
    k_gather1<<<2048, 256, 0, stream>>>(buf0, dinv, rowstart, csr_src, csr_w, b1,
                                        buf1, gsum, gsumsq);                       // H1

    // ---- BN1 -> GEMM2 -> gather2 (fused bias+relu+stats+pool) ----
    k_bnfinal<<<1, 64, 0, stream>>>(gsum, gsumsq, g1, be1, scale, shift);
    k_foldbias<<<1, 64, 0, stream>>>(W2, shift, cshift);
    k_gemm<<<(N_NODES + 63) / 64, 256, 0, stream>>>(buf1, W2, scale, cshift, buf0); // T2
    hipMemsetAsync(gsum, 0, 2 * DIM * sizeof(float), stream);
    k_gather2<<<2048, 256, 0, stream>>>(buf0, dinv, rowstart, csr_src, csr_w, b2,
                                        batch, pool, gsum, gsumsq);

    // ---- BN2 (applied post-pool; BN is affine, pool is linear) -> linear ----
    k_bnfinal<<<1, 64, 0, stream>>>(gsum, gsumsq, g2, be2, scale, shift);
    k_final<<<N_GRAPHS, 64, 0, stream>>>(pool, cnt, scale, shift, Wout, bout, out);
}

// Round 4
// 608.904 us; speedup vs baseline: 1.6407x; 1.0356x over previous
//
#include <hip/hip_runtime.h>
#include <math.h>

#define N_NODES 100000
#define N_EDGES 1280000
#define DIM 64
#define N_GRAPHS 1000
#define BN_EPS 1e-5f
#define SCAN_BLOCKS 392   // 392*256 = 100352 >= N_NODES

// ---- bf16 helpers (OCP bf16 = top 16 bits of fp32, RTN pack) ----
__device__ __forceinline__ unsigned int bf16_rtn2(float a, float b) {
    unsigned int ua = __float_as_uint(a);
    unsigned int ub = __float_as_uint(b);
    ua = (ua + 0x7FFFu + ((ua >> 16) & 1u)) >> 16;
    ub = (ub + 0x7FFFu + ((ub >> 16) & 1u)) >> 16;
    return ua | (ub << 16);
}
__device__ __forceinline__ float bflo(unsigned int u) { return __uint_as_float(u << 16); }
__device__ __forceinline__ float bfhi(unsigned int u) { return __uint_as_float(u & 0xFFFF0000u); }

// ---------------- degree + per-graph count (merged) ----------------
__global__ void k_degcnt(const int* __restrict__ ei, const int* __restrict__ batch,
                         int* __restrict__ degc, float* __restrict__ cnt) {
    int idx = blockIdx.x * blockDim.x + threadIdx.x;
    if (idx < N_EDGES) atomicAdd(&degc[ei[N_EDGES + idx]], 1);
    if (idx < N_NODES) atomicAdd(&cnt[batch[idx]], 1.f);
}

// ---------------- 3-step exclusive scan of deg -> rowstart ----------------
__global__ void k_scan1(const int* __restrict__ deg, int* __restrict__ iscan,
                        int* __restrict__ bsum) {
    __shared__ int ls[256];
    int i = blockIdx.x * 256 + threadIdx.x;
    int v = (i < N_NODES) ? deg[i] : 0;
    ls[threadIdx.x] = v;
    __syncthreads();
    for (int off = 1; off < 256; off <<= 1) {
        int t = (threadIdx.x >= off) ? ls[threadIdx.x - off] : 0;
        __syncthreads();
        ls[threadIdx.x] += t;
        __syncthreads();
    }
    if (i < N_NODES) iscan[i] = ls[threadIdx.x];
    if (threadIdx.x == 255) bsum[blockIdx.x] = ls[255];
}

__global__ void k_scan2(const int* __restrict__ bsum, int* __restrict__ boff) {
    __shared__ int ls[512];
    int t = threadIdx.x;
    int v0 = (t < SCAN_BLOCKS) ? bsum[t] : 0;
    ls[t] = v0;
    __syncthreads();
    for (int off = 1; off < 512; off <<= 1) {
        int v = (t >= off) ? ls[t - off] : 0;
        __syncthreads();
        ls[t] += v;
        __syncthreads();
    }
    if (t < SCAN_BLOCKS) boff[t] = ls[t] - v0;  // exclusive
}

// rowstart + cursor + dinv in one pass
__global__ void k_scan3(const int* __restrict__ deg, const int* __restrict__ iscan,
                        const int* __restrict__ boff, int* __restrict__ rowstart,
                        int* __restrict__ cursor, float* __restrict__ dinv) {
    int i = blockIdx.x * 256 + threadIdx.x;
    if (i < N_NODES) {
        int rs = boff[blockIdx.x] + iscan[i] - deg[i];
        rowstart[i] = rs;
        cursor[i] = rs;
        dinv[i] = 1.0f / sqrtf((float)(deg[i] + 1));
    }
    if (i == 0) rowstart[N_NODES] = N_EDGES;
}

// fill CSR (by destination): csr_ew[pos] = {src, bits(dinv[src]*dinv[dst])}
__global__ void k_fill(const int* __restrict__ ei, const float* __restrict__ dinv,
                       int* __restrict__ cursor, int2* __restrict__ csr_ew) {
    int e = blockIdx.x * blockDim.x + threadIdx.x;
    if (e < N_EDGES) {
        int r = ei[e], c = ei[N_EDGES + e];
        int pos = atomicAdd(&cursor[c], 1);
        csr_ew[pos] = make_int2(r, (int)__float_as_uint(dinv[r] * dinv[c]));
    }
}

// ---------------- input BN statistics ----------------
__global__ void k_stats_x(const float* __restrict__ X,
                          float* __restrict__ gsum, float* __restrict__ gsumsq) {
    int j = threadIdx.x & 63, rg = threadIdx.x >> 6;
    float s = 0.f, s2 = 0.f;
    for (int i = blockIdx.x * 4 + rg; i < N_NODES; i += gridDim.x * 4) {
        float v = X[i * DIM + j];
        s += v; s2 += v * v;
    }
    __shared__ float ls[256], ls2[256];
    ls[threadIdx.x] = s; ls2[threadIdx.x] = s2;
    __syncthreads();
    if (threadIdx.x < 64) {
        s  = ls[j]  + ls[64 + j]  + ls[128 + j]  + ls[192 + j];
        s2 = ls2[j] + ls2[64 + j] + ls2[128 + j] + ls2[192 + j];
        atomicAdd(&gsum[j], s);
        atomicAdd(&gsumsq[j], s2);
    }
}

// scale/shift + folded cshift in one single-block kernel
__global__ void k_bnfold(const float* __restrict__ gsum, const float* __restrict__ gsumsq,
                         const float* __restrict__ g, const float* __restrict__ b,
                         const float* __restrict__ W,
                         float* __restrict__ scale, float* __restrict__ cshift) {
    int j = threadIdx.x;
    float mean = gsum[j] * (1.0f / N_NODES);
    float var  = gsumsq[j] * (1.0f / N_NODES) - mean * mean;
    float inv  = 1.0f / sqrtf(var + BN_EPS);
    float sc   = g[j] * inv;
    scale[j] = sc;
    __shared__ float shl[64];
    shl[j] = b[j] - mean * sc;
    __syncthreads();
    float s = 0.f;
    for (int k = 0; k < DIM; k++) s += shl[k] * W[k * DIM + j];
    cshift[j] = s;
}

// plain BN coefficients (for the post-pool BN2)
__global__ void k_bnfinal(const float* __restrict__ gsum, const float* __restrict__ gsumsq,
                          const float* __restrict__ g, const float* __restrict__ b,
                          float* __restrict__ scale, float* __restrict__ shift) {
    int j = threadIdx.x;
    float mean = gsum[j] * (1.0f / N_NODES);
    float var  = gsumsq[j] * (1.0f / N_NODES) - mean * mean;
    float inv  = 1.0f / sqrtf(var + BN_EPS);
    float sc   = g[j] * inv;
    scale[j] = sc;
    shift[j] = b[j] - mean * sc;
}

// ---------------- GEMM: T(bf16) = (X*scale) @ W + cshift ----------------
__global__ __launch_bounds__(256) void k_gemm(const float* __restrict__ X,
                                              const float* __restrict__ W,
                                              const float* __restrict__ scale,
                                              const float* __restrict__ cshift,
                                              unsigned short* __restrict__ T) {
    __shared__ float Wl[64 * 64];
    __shared__ float Al[64 * 65];
    for (int t = threadIdx.x; t < 4096; t += 256) {
        int k = t >> 6;
        Wl[t] = W[t] * scale[k];
    }
    int row0 = blockIdx.x * 64;
    for (int t = threadIdx.x; t < 4096; t += 256) {
        int r = t >> 6, k = t & 63;
        int i = row0 + r;
        Al[r * 65 + k] = (i < N_NODES) ? X[i * DIM + k] : 0.f;
    }
    __syncthreads();

    int r = threadIdx.x & 63;
    int q = threadIdx.x >> 6;
    float acc[16];
    #pragma unroll
    for (int jj = 0; jj < 16; jj++) acc[jj] = cshift[q * 16 + jj];

    #pragma unroll 4
    for (int k = 0; k < 64; k++) {
        float a = Al[r * 65 + k];
        const float4* wv = (const float4*)&Wl[k * 64 + q * 16];
        float4 w0 = wv[0], w1 = wv[1], w2 = wv[2], w3 = wv[3];
        acc[0]  += a * w0.x; acc[1]  += a * w0.y; acc[2]  += a * w0.z; acc[3]  += a * w0.w;
        acc[4]  += a * w1.x; acc[5]  += a * w1.y; acc[6]  += a * w1.z; acc[7]  += a * w1.w;
        acc[8]  += a * w2.x; acc[9]  += a * w2.y; acc[10] += a * w2.z; acc[11] += a * w2.w;
        acc[12] += a * w3.x; acc[13] += a * w3.y; acc[14] += a * w3.z; acc[15] += a * w3.w;
    }
    int i = row0 + r;
    if (i < N_NODES) {
        unsigned int pk[8];
        #pragma unroll
        for (int jj = 0; jj < 8; jj++) pk[jj] = bf16_rtn2(acc[2 * jj], acc[2 * jj + 1]);
        uint4* outv = (uint4*)&T[(size_t)i * DIM + q * 16];
        outv[0] = make_uint4(pk[0], pk[1], pk[2], pk[3]);
        outv[1] = make_uint4(pk[4], pk[5], pk[6], pk[7]);
    }
}

// ---------------- gather conv layer 1 ----------------
// wave = 8 edge-slots x 8 lanes; lane handles 8 features (uint4 of bf16 = 16B).
// 8 independent 128B row gathers in flight; row = 1 cache line.
__global__ __launch_bounds__(256) void k_gather1(const unsigned short* __restrict__ T,
                                                 const float* __restrict__ dinv,
                                                 const int* __restrict__ rowstart,
                                                 const int2* __restrict__ csr_ew,
                                                 const float* __restrict__ bias,
                                                 float* __restrict__ H,
                                                 float* __restrict__ gsum,
                                                 float* __restrict__ gsumsq) {
    int lane = threadIdx.x & 63;
    int sub  = lane >> 3;        // edge slot 0..7
    int fg   = lane & 7;         // feature group: features 8*fg..8*fg+7
    int wv   = threadIdx.x >> 6;
    int wid = blockIdx.x * 4 + wv;
    int nw = gridDim.x * 4;
    int per = (N_NODES + nw - 1) / nw;
    int i0 = wid * per;
    int i1 = min(i0 + per, N_NODES);
    const uint4* T4 = (const uint4*)T;   // row = 8 uint4
    float4 b0 = ((const float4*)bias)[2 * fg];
    float4 b1 = ((const float4*)bias)[2 * fg + 1];
    float s[8], s2[8];
    #pragma unroll
    for (int c = 0; c < 8; c++) { s[c] = 0.f; s2[c] = 0.f; }
    for (int i = i0; i < i1; i++) {
        int e0 = rowstart[i], e1 = rowstart[i + 1];
        float acc[8];
        #pragma unroll
        for (int c = 0; c < 8; c++) acc[c] = 0.f;
        for (int eb = e0 + sub; eb < e1; eb += 8) {
            int2 ew = csr_ew[eb];                 // broadcast within slot
            float w = __uint_as_float((unsigned int)ew.y);
            uint4 t = T4[(size_t)ew.x * 8 + fg];
            acc[0] += bflo(t.x) * w; acc[1] += bfhi(t.x) * w;
            acc[2] += bflo(t.y) * w; acc[3] += bfhi(t.y) * w;
            acc[4] += bflo(t.z) * w; acc[5] += bfhi(t.z) * w;
            acc[6] += bflo(t.w) * w; acc[7] += bfhi(t.w) * w;
        }
        // butterfly over the slot bits (3,4,5) -> every lane has the full edge sum
        #pragma unroll
        for (int off = 8; off < 64; off <<= 1) {
            #pragma unroll
            for (int c = 0; c < 8; c++) acc[c] += __shfl_xor(acc[c], off, 64);
        }
        // self-loop + bias + relu (all lanes compute; sub==0 stores)
        float di = dinv[i];
        float sw = di * di;
        uint4 ts = T4[(size_t)i * 8 + fg];
        float h[8];
        h[0] = fmaxf(acc[0] + bflo(ts.x) * sw + b0.x, 0.f);
        h[1] = fmaxf(acc[1] + bfhi(ts.x) * sw + b0.y, 0.f);
        h[2] = fmaxf(acc[2] + bflo(ts.y) * sw + b0.z, 0.f);
        h[3] = fmaxf(acc[3] + bfhi(ts.y) * sw + b0.w, 0.f);
        h[4] = fmaxf(acc[4] + bflo(ts.z) * sw + b1.x, 0.f);
        h[5] = fmaxf(acc[5] + bfhi(ts.z) * sw + b1.y, 0.f);
        h[6] = fmaxf(acc[6] + bflo(ts.w) * sw + b1.z, 0.f);
        h[7] = fmaxf(acc[7] + bfhi(ts.w) * sw + b1.w, 0.f);
        if (sub == 0) {
            float4* Hv = (float4*)&H[(size_t)i * DIM + 8 * fg];
            Hv[0] = make_float4(h[0], h[1], h[2], h[3]);
            Hv[1] = make_float4(h[4], h[5], h[6], h[7]);
            #pragma unroll
            for (int c = 0; c < 8; c++) { s[c] += h[c]; s2[c] += h[c] * h[c]; }
        }
    }
    __shared__ float ls[4 * 64], ls2[4 * 64];
    if (sub == 0) {
        #pragma unroll
        for (int c = 0; c < 8; c++) {
            ls[wv * 64 + 8 * fg + c]  = s[c];
            ls2[wv * 64 + 8 * fg + c] = s2[c];
        }
    }
    __syncthreads();
    if (threadIdx.x < 64) {
        int j = threadIdx.x;
        float a  = ls[j]  + ls[64 + j]  + ls[128 + j]  + ls[192 + j];
        float a2 = ls2[j] + ls2[64 + j] + ls2[128 + j] + ls2[192 + j];
        atomicAdd(&gsum[j], a);
        atomicAdd(&gsumsq[j], a2);
    }
}

// ---------------- gather conv layer 2: relu -> pool + BN stats (H2 never stored) ----------------
__global__ __launch_bounds__(256) void k_gather2(const unsigned short* __restrict__ T,
                                                 const float* __restrict__ dinv,
                                                 const int* __restrict__ rowstart,
                                                 const int2* __restrict__ csr_ew,
                                                 const float* __restrict__ bias,
                                                 const int* __restrict__ batch,
                                                 float* __restrict__ pool,
                                                 float* __restrict__ gsum,
                                                 float* __restrict__ gsumsq) {
    int lane = threadIdx.x & 63;
    int sub  = lane >> 3;
    int fg   = lane & 7;
    int wv   = threadIdx.x >> 6;
    int wid = blockIdx.x * 4 + wv;
    int nw = gridDim.x * 4;
    int per = (N_NODES + nw - 1) / nw;
    int i0 = wid * per;
    int i1 = min(i0 + per, N_NODES);
    const uint4* T4 = (const uint4*)T;
    float4 b0 = ((const float4*)bias)[2 * fg];
    float4 b1 = ((const float4*)bias)[2 * fg + 1];
    float s[8], s2[8], ps[8];
    #pragma unroll
    for (int c = 0; c < 8; c++) { s[c] = 0.f; s2[c] = 0.f; ps[c] = 0.f; }
    int cur_g = -1;
    for (int i = i0; i < i1; i++) {
        int e0 = rowstart[i], e1 = rowstart[i + 1];
        float acc[8];
        #pragma unroll
        for (int c = 0; c < 8; c++) acc[c] = 0.f;
        for (int eb = e0 + sub; eb < e1; eb += 8) {
            int2 ew = csr_ew[eb];
            float w = __uint_as_float((unsigned int)ew.y);
            uint4 t = T4[(size_t)ew.x * 8 + fg];
            acc[0] += bflo(t.x) * w; acc[1] += bfhi(t.x) * w;
            acc[2] += bflo(t.y) * w; acc[3] += bfhi(t.y) * w;
            acc[4] += bflo(t.z) * w; acc[5] += bfhi(t.z) * w;
            acc[6] += bflo(t.w) * w; acc[7] += bfhi(t.w) * w;
        }
        #pragma unroll
        for (int off = 8; off < 64; off <<= 1) {
            #pragma unroll
            for (int c = 0; c < 8; c++) acc[c] += __shfl_xor(acc[c], off, 64);
        }
        float di = dinv[i];
        float sw = di * di;
        uint4 ts = T4[(size_t)i * 8 + fg];
        float h[8];
        h[0] = fmaxf(acc[0] + bflo(ts.x) * sw + b0.x, 0.f);
        h[1] = fmaxf(acc[1] + bfhi(ts.x) * sw + b0.y, 0.f);
        h[2] = fmaxf(acc[2] + bflo(ts.y) * sw + b0.z, 0.f);
        h[3] = fmaxf(acc[3] + bfhi(ts.y) * sw + b0.w, 0.f);
        h[4] = fmaxf(acc[4] + bflo(ts.z) * sw + b1.x, 0.f);
        h[5] = fmaxf(acc[5] + bfhi(ts.z) * sw + b1.y, 0.f);
        h[6] = fmaxf(acc[6] + bflo(ts.w) * sw + b1.z, 0.f);
        h[7] = fmaxf(acc[7] + bfhi(ts.w) * sw + b1.w, 0.f);
        if (sub == 0) {
            #pragma unroll
            for (int c = 0; c < 8; c++) { s[c] += h[c]; s2[c] += h[c] * h[c]; }
            int g = batch[i];                  // sorted -> rarely changes
            if (g != cur_g) {
                if (cur_g >= 0) {
                    #pragma unroll
                    for (int c = 0; c < 8; c++)
                        atomicAdd(&pool[(size_t)cur_g * DIM + 8 * fg + c], ps[c]);
                }
                #pragma unroll
                for (int c = 0; c < 8; c++) ps[c] = 0.f;
                cur_g = g;
            }
            #pragma unroll
            for (int c = 0; c < 8; c++) ps[c] += h[c];
        }
    }
    if (sub == 0 && cur_g >= 0) {
        #pragma unroll
        for (int c = 0; c < 8; c++)
            atomicAdd(&pool[(size_t)cur_g * DIM + 8 * fg + c], ps[c]);
    }
    __shared__ float ls[4 * 64], ls2[4 * 64];
    if (sub == 0) {
        #pragma unroll
        for (int c = 0; c < 8; c++) {
            ls[wv * 64 + 8 * fg + c]  = s[c];
            ls2[wv * 64 + 8 * fg + c] = s2[c];
        }
    }
    __syncthreads();
    if (threadIdx.x < 64) {
        int j = threadIdx.x;
        float a  = ls[j]  + ls[64 + j]  + ls[128 + j]  + ls[192 + j];
        float a2 = ls2[j] + ls2[64 + j] + ls2[128 + j] + ls2[192 + j];
        atomicAdd(&gsum[j], a);
        atomicAdd(&gsumsq[j], a2);
    }
}

// ---------------- final: out[g] = ((pool/cnt)*scale + shift) @ Wout + bout ----------------
__global__ void k_final(const float* __restrict__ pool, const float* __restrict__ cnt,
                        const float* __restrict__ scale, const float* __restrict__ shift,
                        const float* __restrict__ Wout, const float* __restrict__ bout,
                        float* __restrict__ out) {
    int g = blockIdx.x;
    int l = threadIdx.x;
    float c = fmaxf(cnt[g], 1.f);
    float p = (pool[g * DIM + l] / c) * scale[l] + shift[l];
    float a0 = p * Wout[l * 2 + 0];
    float a1 = p * Wout[l * 2 + 1];
    #pragma unroll
    for (int off = 32; off; off >>= 1) {
        a0 += __shfl_down(a0, off, 64);
        a1 += __shfl_down(a1, off, 64);
    }
    if (l == 0) {
        out[g * 2 + 0] = a0 + bout[0];
        out[g * 2 + 1] = a1 + bout[1];
    }
}

extern "C" void kernel_launch(void* const* d_in, const int* in_sizes, int n_in,
                              void* d_out, int out_size, void* d_ws, size_t ws_size,
                              hipStream_t stream) {
    (void)in_sizes; (void)n_in; (void)out_size; (void)ws_size;
    const float* x       = (const float*)d_in[0];
    const int*   ei      = (const int*)d_in[1];
    const int*   batch   = (const int*)d_in[2];
    const float* bn_in_g = (const float*)d_in[3];
    const float* bn_in_b = (const float*)d_in[4];
    const float* W1      = (const float*)d_in[5];
    const float* b1      = (const float*)d_in[6];
    const float* g1      = (const float*)d_in[7];
    const float* be1     = (const float*)d_in[8];
    const float* W2      = (const float*)d_in[9];
    const float* b2      = (const float*)d_in[10];
    const float* g2      = (const float*)d_in[11];
    const float* be2     = (const float*)d_in[12];
    const float* Wout    = (const float*)d_in[13];
    const float* bout    = (const float*)d_in[14];
    float* out = (float*)d_out;

    // workspace layout (~51 MB), 8B alignment maintained for csr_ew
    char* p = (char*)d_ws;
    float* H = (float*)p;             p += (size_t)N_NODES * DIM * 4;      // 25.6 MB fp32
    unsigned short* T = (unsigned short*)p; p += (size_t)N_NODES * DIM * 2; // 12.8 MB bf16
    float* dinv = (float*)p;          p += N_NODES * 4;
    int* degc = (int*)p;              p += N_NODES * 4;
    int* iscan = (int*)p;             p += N_NODES * 4;
    int* rowstart = (int*)p;          p += (N_NODES + 2) * 4;              // +2 keeps 8B align
    int* cursor = (int*)p;            p += N_NODES * 4;
    int2* csr_ew = (int2*)p;          p += (size_t)N_EDGES * 8;            // 10.24 MB
    int* bsum = (int*)p;              p += SCAN_BLOCKS * 4;
    int* boff = (int*)p;              p += SCAN_BLOCKS * 4;
    float* gsum = (float*)p;          p += DIM * 4;
    float* gsumsq = (float*)p;        p += DIM * 4;
    float* scale = (float*)p;         p += DIM * 4;
    float* shift = (float*)p;         p += DIM * 4;
    float* cshift = (float*)p;        p += DIM * 4;
    float* pool = (float*)p;          p += (size_t)N_GRAPHS * DIM * 4;
    float* cnt = (float*)p;           p += N_GRAPHS * 4;

    // ---- CSR build + norm coefficients ----
    hipMemsetAsync(degc, 0, N_NODES * sizeof(int), stream);
    hipMemsetAsync(pool, 0, (N_GRAPHS * DIM + N_GRAPHS) * sizeof(float), stream);
    k_degcnt<<<(N_EDGES + 255) / 256, 256, 0, stream>>>(ei, batch, degc, cnt);
    k_scan1<<<SCAN_BLOCKS, 256, 0, stream>>>(degc, iscan, bsum);
    k_scan2<<<1, 512, 0, stream>>>(bsum, boff);
    k_scan3<<<SCAN_BLOCKS, 256, 0, stream>>>(degc, iscan, boff, rowstart, cursor, dinv);
    k_fill<<<N_EDGES / 256, 256, 0, stream>>>(ei, dinv, cursor, csr_ew);

    // ---- input BN -> GEMM1 -> gather1 (fused bias+relu+stats) ----
    hipMemsetAsync(gsum, 0, 2 * DIM * sizeof(float), stream);
    k_stats_x<<<1024, 256, 0, stream>>>(x, gsum, gsumsq);
    k_bnfold<<<1, 64, 0, stream>>>(gsum, gsumsq, bn_in_g, bn_in_b, W1, scale, cshift);
    k_gemm<<<(N_NODES + 63) / 64, 256, 0, stream>>>(x, W1, scale, cshift, T);      // T1 (bf16)
    hipMemsetAsync(gsum, 0, 2 * DIM * sizeof(float), stream);
    k_gather1<<<2048, 256, 0, stream>>>(T, dinv, rowstart, csr_ew, b1, H, gsum, gsumsq); // H1 fp32

    // ---- BN1 -> GEMM2 -> gather2 (fused bias+relu+stats+pool) ----
    k_bnfold<<<1, 64, 0, stream>>>(gsum, gsumsq, g1, be1, W2, scale, cshift);
    k_gemm<<<(N_NODES + 63) / 64, 256, 0, stream>>>(H, W2, scale, cshift, T);      // T2 (bf16)
    hipMemsetAsync(gsum, 0, 2 * DIM * sizeof(float), stream);
    k_gather2<<<2048, 256, 0, stream>>>(T, dinv, rowstart, csr_ew, b2, batch, pool,
                                        gsum, gsumsq);

    // ---- BN2 (applied post-pool; BN affine, pool linear) -> linear ----
    k_bnfinal<<<1, 64, 0, stream>>>(gsum, gsumsq, g2, be2, scale, shift);
    k_final<<<N_GRAPHS, 64, 0, stream>>>(pool, cnt, scale, shift, Wout, bout, out);
}